// Round 7
// baseline (196.478 us; speedup 1.0000x reference)
//
#include <hip/hip_runtime.h>
#include <hip/hip_bf16.h>
#include <cstdint>
#include <cstddef>

// Problem constants (from reference)
#define F0v   2048
#define F1v   2304
#define F2v   2560
#define E1v   256
#define E2v   256
#define BROWS 8192
#define ODIM  1024
#define NNZv  262144
#define NBv   1024

typedef __bf16 bf16x8 __attribute__((ext_vector_type(8)));
typedef float floatx4 __attribute__((ext_vector_type(4)));

__device__ __forceinline__ unsigned short f2bf(float f) {
  unsigned int u = __float_as_uint(f);
  u += 0x7FFFu + ((u >> 16) & 1u);   // round-to-nearest-even
  return (unsigned short)(u >> 16);
}

__device__ __forceinline__ void async_ld16(const void* g, void* l) {
  __builtin_amdgcn_global_load_lds(
      (const __attribute__((address_space(1))) unsigned int*)g,
      (__attribute__((address_space(3))) unsigned int*)l, 16, 0, 0);
}

// ---------------------------------------------------------------------------
// Kernel 1 (fused): blocks [0,8192) build h rows (one barrier, closed-form
// two-hop tails); blocks [8192,9216) do the COO scatter-add.
// ---------------------------------------------------------------------------
__global__ __launch_bounds__(256) void fused_pre_kernel(
    const float* __restrict__ x, const float* __restrict__ e1w,
    const float* __restrict__ e2w, const int* __restrict__ e1p,
    const int* __restrict__ e2p, unsigned short* __restrict__ h,
    const int* __restrict__ wr, const int* __restrict__ wc,
    const float* __restrict__ wv, const int* __restrict__ bidx,
    const float* __restrict__ bv, float* __restrict__ Wd,
    float* __restrict__ bias) {
  __shared__ float xrow[F0v];
  __shared__ int   tsrc[E1v + E2v];
  __shared__ float twa[E1v + E2v];
  __shared__ float twb[E1v + E2v];
  const int tid = threadIdx.x;

  if (blockIdx.x >= BROWS) {
    int gid = (blockIdx.x - BROWS) * 256 + tid;
    if (gid < NNZv)
      atomicAdd(&Wd[(size_t)wr[gid] * F2v + wc[gid]], wv[gid]);
    if (gid < NBv)
      atomicAdd(&bias[bidx[gid]], bv[gid]);
    return;
  }

  const int b = blockIdx.x;
  const float* xr = x + (size_t)b * F0v;
  unsigned short* hr = h + (size_t)b * F2v;

  {
    tsrc[tid] = e1p[tid]; twa[tid] = e1w[tid]; twb[tid] = 1.0f;
    int p2 = e2p[tid]; float w2 = e2w[tid];
    if (p2 < F0v) {
      tsrc[E1v + tid] = p2;  twa[E1v + tid] = w2;  twb[E1v + tid] = 1.0f;
    } else {
      int q = p2 - F0v;
      tsrc[E1v + tid] = e1p[q]; twa[E1v + tid] = e1w[q]; twb[E1v + tid] = w2;
    }
  }

  float4 v0 = ((const float4*)xr)[tid * 2];
  float4 v1 = ((const float4*)xr)[tid * 2 + 1];
  ((float4*)xrow)[tid * 2] = v0;
  ((float4*)xrow)[tid * 2 + 1] = v1;
  union { unsigned short us[8]; uint4 u4; } pk;
  pk.us[0] = f2bf(v0.x); pk.us[1] = f2bf(v0.y);
  pk.us[2] = f2bf(v0.z); pk.us[3] = f2bf(v0.w);
  pk.us[4] = f2bf(v1.x); pk.us[5] = f2bf(v1.y);
  pk.us[6] = f2bf(v1.z); pk.us[7] = f2bf(v1.w);
  ((uint4*)hr)[tid] = pk.u4;
  __syncthreads();

  int j0 = tid * 2;
  float a0 = fmaxf(fmaxf(xrow[tsrc[j0]] * twa[j0], 0.0f) * twb[j0], 0.0f);
  float a1 = fmaxf(fmaxf(xrow[tsrc[j0 + 1]] * twa[j0 + 1], 0.0f) * twb[j0 + 1], 0.0f);
  unsigned int packed = (unsigned int)f2bf(a0) | ((unsigned int)f2bf(a1) << 16);
  ((unsigned int*)(hr + F0v))[tid] = packed;
}

// ---------------------------------------------------------------------------
// Kernel 2: W f32 -> bf16 (8 elems/thread)
// ---------------------------------------------------------------------------
__global__ __launch_bounds__(256) void convert_kernel(
    const float* __restrict__ Wd, unsigned short* __restrict__ Wb) {
  int gid = blockIdx.x * 256 + threadIdx.x;
  const float4* src = (const float4*)Wd;
  float4 a = src[gid * 2];
  float4 b = src[gid * 2 + 1];
  union { unsigned short us[8]; uint4 u4; } pk;
  pk.us[0] = f2bf(a.x); pk.us[1] = f2bf(a.y);
  pk.us[2] = f2bf(a.z); pk.us[3] = f2bf(a.w);
  pk.us[4] = f2bf(b.x); pk.us[5] = f2bf(b.y);
  pk.us[6] = f2bf(b.z); pk.us[7] = f2bf(b.w);
  ((uint4*)Wb)[gid] = pk.u4;
}

// ---------------------------------------------------------------------------
// Kernel 3: C = h @ W^T + bias.  128x128 tile, 256 threads (4 waves, 2x2),
// wave-tile 64x64 = acc[4][4] of 16x16x32 bf16 MFMA.  BK=32 with FOUR LDS
// buffers and prefetch distance 3, raw s_barrier + fine s_waitcnt vmcnt(8)
// (AITER pattern): loads stay in flight across the barrier, killing the
// vmcnt(0)-drain stall that capped R6 at 31% MfmaUtil.
// Per-iter protocol (each wave):
//   s_waitcnt vmcnt(8)  -> own fill for CURRENT buf landed (2 newer in flight)
//   s_barrier (raw)     -> all waves' fills landed; buf cur-1 fully consumed
//   fill buf cur+3      -> safe overwrite (post-barrier)
//   8 ds_read_b128 + 16 MFMA (R3 conflict-free pattern: seg=(quad+(r16>>1))&3)
// LDS = 4 x (8+8) KB = 64 KB -> 2 blocks/CU (same as R6).
// ---------------------------------------------------------------------------
#define BM 128
#define BN 128
#define BK 32
#define NBUF 4

__global__ __launch_bounds__(256) void gemm_bt_kernel(
    const unsigned short* __restrict__ A,
    const unsigned short* __restrict__ Bw,
    const float* __restrict__ bias,
    float* __restrict__ C) {
  __shared__ unsigned short As[NBUF][BM * BK];   // 4 x 8 KB
  __shared__ unsigned short Bs[NBUF][BN * BK];   // 4 x 8 KB
  const int tid = threadIdx.x;
  const int wave = tid >> 6;      // 0..3
  const int lane = tid & 63;

  // XCD swizzle: grid (8, 64); id%8 = XCD. XCD k owns M-tiles [8k,8k+8).
  const int id = blockIdx.y * 8 + blockIdx.x;
  const int ty = (id & 7) * 8 + ((id >> 3) & 7);   // M-tile 0..63
  const int tx = id >> 6;                          // N-tile 0..7
  const int m0 = ty * BM;
  const int n0 = tx * BN;
  const int wm = wave >> 1;       // 0..1  (64-row half of M)
  const int wn = wave & 1;        // 0..1  (64-col half of N)
  const int quad = lane >> 4;     // 0..3
  const int r16 = lane & 15;

  // Staging (R3's verified map): chunk = 16 rows x 32 cols (1 KiB); A,B each
  // 8 chunks; wave w stages chunks {2w,2w+1} of both. Lane L: row L/4,
  // stored seg L%4, sourcing global seg (L%4 - (row>>1)) & 3.
  const int lr = lane >> 2;                       // 0..15 row in chunk
  const int ls = lane & 3;                        // stored 16B seg
  const int gs = (ls - (lr >> 1)) & 3;            // global 16B seg
  const unsigned short* pA0 = A + (size_t)(m0 + wave * 32 + lr) * F2v + gs * 8;
  const unsigned short* pA1 = pA0 + (size_t)16 * F2v;
  const unsigned short* pB0 = Bw + (size_t)(n0 + wave * 32 + lr) * F2v + gs * 8;
  const unsigned short* pB1 = pB0 + (size_t)16 * F2v;
  const int lOff = wave * 1024;                   // wave-uniform LDS chunk base

  floatx4 acc[4][4];
  floatx4 zz = {0.f, 0.f, 0.f, 0.f};
#pragma unroll
  for (int i = 0; i < 4; ++i)
#pragma unroll
    for (int j = 0; j < 4; ++j) acc[i][j] = zz;

  // prologue: fill bufs 0,1,2 for k = 0,32,64  (12 loads in flight per lane)
#pragma unroll
  for (int p = 0; p < 3; ++p) {
    async_ld16(pA0 + p * BK, &As[p][lOff]);
    async_ld16(pA1 + p * BK, &As[p][lOff + 512]);
    async_ld16(pB0 + p * BK, &Bs[p][lOff]);
    async_ld16(pB1 + p * BK, &Bs[p][lOff + 512]);
  }

  // fragment stored-seg: (quad + (r16>>1)) & 3  (R3 measured-zero conflicts)
  const int fseg = ((quad + (r16 >> 1)) & 3) * 8;

#pragma unroll 4
  for (int k0 = 0; k0 < F2v; k0 += BK) {
    const int cb = (k0 >> 5) & 3;
    const int rem = F2v - k0;
    // wait for own fill of buf cb (issued 3 iters ago); keep newer in flight
    if (rem > 64)      asm volatile("s_waitcnt vmcnt(8)" ::: "memory");
    else if (rem > 32) asm volatile("s_waitcnt vmcnt(4)" ::: "memory");
    else               asm volatile("s_waitcnt vmcnt(0)" ::: "memory");
    asm volatile("s_barrier" ::: "memory");
    if (k0 + 3 * BK < F2v) {
      const int nb = (cb + 3) & 3;
      const int kt = k0 + 3 * BK;
      async_ld16(pA0 + kt, &As[nb][lOff]);
      async_ld16(pA1 + kt, &As[nb][lOff + 512]);
      async_ld16(pB0 + kt, &Bs[nb][lOff]);
      async_ld16(pB1 + kt, &Bs[nb][lOff + 512]);
    }

    bf16x8 af[4], bfr[4];
#pragma unroll
    for (int mi = 0; mi < 4; ++mi) {
      int row = wm * 64 + mi * 16 + r16;
      af[mi] = *(const bf16x8*)&As[cb][row * BK + fseg];
    }
#pragma unroll
    for (int ni = 0; ni < 4; ++ni) {
      int row = wn * 64 + ni * 16 + r16;
      bfr[ni] = *(const bf16x8*)&Bs[cb][row * BK + fseg];
    }
#pragma unroll
    for (int mi = 0; mi < 4; ++mi)
#pragma unroll
      for (int ni = 0; ni < 4; ++ni)
        acc[mi][ni] = __builtin_amdgcn_mfma_f32_16x16x32_bf16(
            af[mi], bfr[ni], acc[mi][ni], 0, 0, 0);
  }

  // Epilogue: C/D layout col = lane&15, row = quad*4 + reg (m89/m91 verified)
#pragma unroll
  for (int ni = 0; ni < 4; ++ni) {
    int col = n0 + wn * 64 + ni * 16 + r16;
    float bc = bias[col];
#pragma unroll
    for (int mi = 0; mi < 4; ++mi) {
      int row = m0 + wm * 64 + mi * 16 + quad * 4;
#pragma unroll
      for (int rg = 0; rg < 4; ++rg)
        C[(size_t)(row + rg) * ODIM + col] = acc[mi][ni][rg] + bc;
    }
  }
}

// ---------------------------------------------------------------------------
extern "C" void kernel_launch(void* const* d_in, const int* in_sizes, int n_in,
                              void* d_out, int out_size, void* d_ws, size_t ws_size,
                              hipStream_t stream) {
  const float* x    = (const float*)d_in[0];
  const float* e1w  = (const float*)d_in[1];
  const float* e2w  = (const float*)d_in[2];
  const float* wv   = (const float*)d_in[3];
  const float* bv   = (const float*)d_in[4];
  const int*   e1p  = (const int*)d_in[5];
  const int*   e2p  = (const int*)d_in[6];
  const int*   wr   = (const int*)d_in[7];
  const int*   wc   = (const int*)d_in[8];
  const int*   bidx = (const int*)d_in[9];
  float* out = (float*)d_out;

  // Workspace carve (total ~57.7 MB)
  char* ws = (char*)d_ws;
  const size_t h_bytes  = (size_t)BROWS * F2v * 2;        // 41,943,040
  const size_t wd_bytes = (size_t)ODIM * F2v * 4;         // 10,485,760
  const size_t b_bytes  = (size_t)ODIM * 4;               // 4,096
  unsigned short* h   = (unsigned short*)ws;
  float* Wd           = (float*)(ws + h_bytes);
  float* bias         = (float*)(ws + h_bytes + wd_bytes);
  unsigned short* Wb  = (unsigned short*)(ws + h_bytes + wd_bytes + b_bytes);

  hipMemsetAsync(Wd, 0, wd_bytes + b_bytes, stream);
  fused_pre_kernel<<<BROWS + NNZv / 256, 256, 0, stream>>>(
      x, e1w, e2w, e1p, e2p, h, wr, wc, wv, bidx, bv, Wd, bias);
  convert_kernel<<<(ODIM * F2v / 8) / 256, 256, 0, stream>>>(Wd, Wb);
  gemm_bt_kernel<<<dim3(ODIM / BN, BROWS / BM), 256, 0, stream>>>(h, Wb, bias, out);
}